// Round 11
// baseline (102.541 us; speedup 1.0000x reference)
//
#include <hip/hip_runtime.h>
#include <hip/hip_bf16.h>

typedef __attribute__((ext_vector_type(4))) float  float4v;
typedef __attribute__((ext_vector_type(2))) unsigned int uint2v;
typedef __attribute__((ext_vector_type(8))) short  short8v;
typedef __attribute__((ext_vector_type(4))) float  f32x4;

__device__ __forceinline__ unsigned short f2bf(float f) {
    unsigned int u = __float_as_uint(f);
    u += 0x7FFFu + ((u >> 16) & 1u);   // RNE
    return (unsigned short)(u >> 16);
}

// fast tanh: (t-1)/(t+1), t = 2^(2*log2e*x); clamp avoids inf*0 NaN.
__device__ __forceinline__ float ftanh(float x) {
    float s = fminf(x * 2.8853900817779268f, 115.0f);
    float t = exp2f(s);
    return (t - 1.0f) * __builtin_amdgcn_rcpf(t + 1.0f);
}

__device__ __forceinline__ int swzb(int row, int kbyte) {
    // row-major [R][128] bf16 rows (256B); XOR-swizzle bits 4-6 (G4).
    return row * 256 + (kbyte ^ ((row & 7) << 4));
}
__device__ __forceinline__ int swzh(int row, int kbyte) {
    // h1B swizzle: extra (row&8)<<2 spreads lk/lk+2 lanes across banks.
    return row * 256 + (kbyte ^ ((row & 7) << 4) ^ ((row & 8) << 2));
}

// ---------------- K0a: transpose + bf16-cast weights into ws ----------------
__global__ void prep_weights(const float* __restrict__ cw1, const float* __restrict__ cw2,
                             const float* __restrict__ hw1, const float* __restrict__ hw2,
                             unsigned short* __restrict__ w1bT, unsigned short* __restrict__ w2bT,
                             unsigned short* __restrict__ hw1T, unsigned short* __restrict__ hw2T) {
    int i = blockIdx.x * 256 + threadIdx.x;
    if (i < 16384) {                       // w1 top half T: [j<128][k<128]
        int j = i >> 7, k = i & 127;
        w1bT[i] = f2bf(cw1[k * 128 + j]);
    } else if (i < 24576) {                // w2 T: [j<64][k<128]
        int t = i - 16384; int j = t >> 7, k = t & 127;
        w2bT[t] = f2bf(cw2[k * 64 + j]);
    } else if (i < 28672) {                // hw1 top 128 rows T: [j<32][k<128]
        int t = i - 24576; int j = t >> 7, k = t & 127;
        hw1T[t] = f2bf(hw1[k * 32 + j]);
    } else if (i < 29184) {                // hw2 T: [j<16][k<32]
        int t = i - 28672; int j = t >> 5, k = t & 31;
        hw2T[t] = f2bf(hw2[k * 16 + j]);
    }
}

// ---------------- K0b: ctxW1[bt][j] = ctx[bt] @ W1_bot + cb1 (f32 exact) -----
__global__ __launch_bounds__(256) void ctx_gemm(const float* __restrict__ ctx,
                                                const float* __restrict__ cw1,
                                                const float* __restrict__ cb1,
                                                float* __restrict__ ctxW1) {
    __shared__ float ldsW[128 * 128];   // W1 bottom half [d][j]
    __shared__ float ldsC[16 * 128];    // 16 ctx rows
    const int tid = threadIdx.x;
    const int bt0 = blockIdx.x * 16;
    for (int i = tid; i < 16384; i += 256) {
        int d = i >> 7, j = i & 127;
        ldsW[i] = cw1[(128 + d) * 128 + j];
    }
    for (int i = tid; i < 2048; i += 256) ldsC[i] = ctx[bt0 * 128 + i];
    __syncthreads();
    const int j = tid & 127, half = tid >> 7;
    float acc[8];
    float bj = cb1[j];
#pragma unroll
    for (int k = 0; k < 8; ++k) acc[k] = bj;
    for (int d = 0; d < 128; ++d) {
        float wv = ldsW[d * 128 + j];
#pragma unroll
        for (int k = 0; k < 8; ++k) acc[k] += ldsC[(half * 8 + k) * 128 + d] * wv;
    }
#pragma unroll
    for (int k = 0; k < 8; ++k) ctxW1[(size_t)(bt0 + half * 8 + k) * 128 + j] = acc[k];
}

// ------- K1: fused per-(b,t) kernel — 8 waves, 4 barriers, halved per-wave work ---
__global__ __launch_bounds__(512, 6) void fused_main(
    const float* __restrict__ pos_g, const float* __restrict__ dep_g,
    const float* __restrict__ cb2,  const float* __restrict__ cw3,
    const float* __restrict__ cb3,  const float* __restrict__ hw1,
    const float* __restrict__ hb1,  const float* __restrict__ hb2,
    const float* __restrict__ hw3,  const float* __restrict__ hb3,
    const unsigned short* __restrict__ w1bT, const unsigned short* __restrict__ w2bT,
    const unsigned short* __restrict__ hw1T, const unsigned short* __restrict__ hw2T,
    const float* __restrict__ ctxW1g, float* __restrict__ out)
{
    __shared__ __align__(16) short posB[64 * 128];   // 16 KB bf16 positions, swizzled
    __shared__ __align__(16) short h1B[64 * 128];    // 16 KB layer1 out
    __shared__ __align__(16) short g1B[64 * 32];     // 4 KB hier g1
    __shared__ float tdep[64], diag[64], localc[64];
    __shared__ float ctxp[256];                      // [col-tile][row] layer2 partials
    __shared__ float knnp[512];                      // [half][point][4] kNN partials

    const int bt  = blockIdx.x;
    const int tid = threadIdx.x;
    const int w   = tid >> 6;    // 8 waves
    const int lane = tid & 63;
    const int lr  = lane & 15;
    const int lk  = lane >> 4;
    const int rT  = w >> 1;      // row-tile for Gram/hier1/ (and layer2 col-tile)
    const int hT  = w & 1;       // half / col-pair selector

    // ---------------- P0: stage positions (f32 -> bf16, swizzled) ----------------
    {
        const float4v* gp = (const float4v*)(pos_g + (size_t)bt * 8192) + tid;
        const int srow = tid >> 5, sc4 = tid & 31;
        char* lp = (char*)posB + srow * 256 + ((sc4 * 8) ^ ((srow & 7) << 4));
#pragma unroll
        for (int i = 0; i < 4; ++i) {
            float4v v = gp[512 * i];                     // +16 rows = 512 float4/iter
            __hip_bfloat162 lo2 = __float22bfloat162_rn(make_float2(v[0], v[1]));
            __hip_bfloat162 hi2 = __float22bfloat162_rn(make_float2(v[2], v[3]));
            unsigned int u0, u1;
            __builtin_memcpy(&u0, &lo2, 4);
            __builtin_memcpy(&u1, &hi2, 4);
            uint2v uu = {u0, u1};
            *(uint2v*)(lp + 4096 * i) = uu;              // row+16: same swizzle bits
        }
    }
    if (tid < 64) tdep[tid] = ftanh(dep_g[bt * 64 + tid]);
    __syncthreads();                                   // B1: posB/tdep visible

    // ------- P1: Gram — wave w: row-tile rT, col-tiles {2hT, 2hT+1} -------
    f32x4 ga = {0.f,0.f,0.f,0.f}, gb = {0.f,0.f,0.f,0.f};
    {
        const int c0 = 2 * hT;
#pragma unroll
        for (int ks = 0; ks < 4; ++ks) {
            int kb = ks * 64 + lk * 16;
            short8v a  = *(const short8v*)((const char*)posB + swzb(16 * rT + lr, kb));
            short8v b0 = *(const short8v*)((const char*)posB + swzb(16 * c0 + lr, kb));
            short8v b1 = *(const short8v*)((const char*)posB + swzb(16 * c0 + 16 + lr, kb));
            ga = __builtin_amdgcn_mfma_f32_16x16x32_bf16(a, b0, ga, 0, 0, 0);
            gb = __builtin_amdgcn_mfma_f32_16x16x32_bf16(a, b1, gb, 0, 0, 0);
        }
        // diagonal tile (rT,rT): owned by exactly one of the two col-tiles
        bool haveA = (c0 == rT), haveB = (c0 + 1 == rT);
        if (haveA || haveB) {
            f32x4 gd = haveA ? ga : gb;
            int e = lr & 3;
            float dv = (e == 0) ? gd[0] : (e == 1) ? gd[1] : (e == 2) ? gd[2] : gd[3];
            if (lk == (lr >> 2)) diag[16 * rT + lr] = dv;
        }
    }
    __syncthreads();                                   // B2: diag visible

    // ------- P2: kNN partial top-4 over this wave's 32 cols + layer1 --------
    {   // kNN partials (VALU) — hides the w1f global-load latency below
        float s0[4], s1[4], s2[4], s3[4];
#pragma unroll
        for (int e = 0; e < 4; ++e) {
            int p = 16 * rT + 4 * lk + e;
            float dp = diag[p];
            s0[e] = s1[e] = s2[e] = s3[e] = 1e30f;
#pragma unroll
            for (int t = 0; t < 2; ++t) {
                f32x4 gt = (t == 0) ? ga : gb;
                float gv = (e == 0) ? gt[0] : (e == 1) ? gt[1] : (e == 2) ? gt[2] : gt[3];
                float d2 = dp + diag[16 * (2 * hT + t) + lr] - 2.f * gv;
                float c0 = fminf(s0[e], d2), m0 = fmaxf(s0[e], d2);
                float c1 = fminf(s1[e], m0), m1 = fmaxf(s1[e], m0);
                float c2 = fminf(s2[e], m1), m2 = fmaxf(s2[e], m1);
                float c3 = fminf(s3[e], m2);
                s0[e] = c0; s1[e] = c1; s2[e] = c2; s3[e] = c3;
            }
        }
#pragma unroll
        for (int m = 1; m <= 8; m <<= 1) {
#pragma unroll
            for (int e = 0; e < 4; ++e) {
                float t0 = __shfl_xor(s0[e], m);
                float t1 = __shfl_xor(s1[e], m);
                float t2 = __shfl_xor(s2[e], m);
                float t3 = __shfl_xor(s3[e], m);
                float r0 = fminf(s0[e], t3), r1 = fminf(s1[e], t2);
                float r2 = fminf(s2[e], t1), r3 = fminf(s3[e], t0);
                float a0 = fminf(r0, r2), b0 = fmaxf(r0, r2);
                float a1 = fminf(r1, r3), b1 = fmaxf(r1, r3);
                s0[e] = fminf(a0, a1); s1[e] = fmaxf(a0, a1);
                s2[e] = fminf(b0, b1); s3[e] = fmaxf(b0, b1);
            }
        }
        if (lr == 0) {
#pragma unroll
            for (int e = 0; e < 4; ++e) {
                int p = 16 * rT + 4 * lk + e;
                knnp[hT * 256 + p * 4 + 0] = s0[e];
                knnp[hT * 256 + p * 4 + 1] = s1[e];
                knnp[hT * 256 + p * 4 + 2] = s2[e];
                knnp[hT * 256 + p * 4 + 3] = s3[e];
            }
        }
    }
    {   // layer1 col-split: wave w -> cols [16w,16w+16), all 64 rows
        const short8v* w1p8 = (const short8v*)w1bT;
        short8v w1f[4];
#pragma unroll
        for (int ks = 0; ks < 4; ++ks)
            w1f[ks] = w1p8[(16 * w + lr) * 16 + ks * 4 + lk];
        float cval = ctxW1g[(size_t)bt * 128 + 16 * w + lr];
        f32x4 h1a[4];
#pragma unroll
        for (int rt = 0; rt < 4; ++rt) h1a[rt] = (f32x4){0.f,0.f,0.f,0.f};
#pragma unroll
        for (int ks = 0; ks < 4; ++ks) {
            int kb = ks * 64 + lk * 16;
#pragma unroll
            for (int rt = 0; rt < 4; ++rt) {
                short8v a = *(const short8v*)((const char*)posB + swzb(rt * 16 + lr, kb));
                h1a[rt] = __builtin_amdgcn_mfma_f32_16x16x32_bf16(a, w1f[ks], h1a[rt], 0, 0, 0);
            }
        }
        int j = 16 * w + lr;
#pragma unroll
        for (int rt = 0; rt < 4; ++rt)
#pragma unroll
            for (int e = 0; e < 4; ++e) {
                int p = rt * 16 + 4 * lk + e;
                float v = fmaxf(h1a[rt][e] + cval, 0.f);
                *(short*)((char*)h1B + swzh(p, 2 * j)) = (short)f2bf(v);
            }
    }
    __syncthreads();                                   // B3: h1B + knnp visible

    // ------- P3: kNN merge + layer2 + hier1 --------
    // phase-local weight loads first (latency hidden under merge VALU)
    const short8v* w2p8 = (const short8v*)w2bT;
    const short8v* hw1p8 = (const short8v*)hw1T;
    short8v w2f[4], hw1f[4];
#pragma unroll
    for (int ks = 0; ks < 4; ++ks) {
        w2f[ks]  = w2p8[(16 * rT + lr) * 16 + ks * 4 + lk];    // layer2 col-tile rT
        hw1f[ks] = hw1p8[(16 * hT + lr) * 16 + ks * 4 + lk];   // hier1 col-half hT
    }
    float cb2v = cb2[16 * rT + lr], cw3v = cw3[16 * rT + lr];
    float u1v = hw1[4096 + 16 * hT + lr], hb1v = hb1[16 * hT + lr];

    if (tid < 64) {   // kNN merge: two sorted 4-lists -> global 4 smallest
        int p = tid;
        float a0 = knnp[p * 4 + 0], a1 = knnp[p * 4 + 1], a2 = knnp[p * 4 + 2], a3 = knnp[p * 4 + 3];
        float b0 = knnp[256 + p * 4 + 0], b1 = knnp[256 + p * 4 + 1],
              b2 = knnp[256 + p * 4 + 2], b3 = knnp[256 + p * 4 + 3];
        float m0 = fminf(a0, b3), m1 = fminf(a1, b2), m2 = fminf(a2, b1), m3 = fminf(a3, b0);
        float x0 = fminf(m0, m2), x2 = fmaxf(m0, m2), x1 = fminf(m1, m3), x3 = fmaxf(m1, m3);
        float s1 = fmaxf(fminf(x0, x1), 0.f) * 0.f + fmaxf(fminf(x0, x1), fminf(x0, x1)); // s0 unused
        s1 = fmaxf(x0, x1) < fminf(x2, x3) ? fmaxf(x0, x1) : fmaxf(x0, x1); // keep simple below
        float q1 = fmaxf(x0, x1);            // 2nd smallest
        float q2 = fminf(x2, x3);            // 3rd
        float q3 = fmaxf(x2, x3);            // 4th
        float d1 = __builtin_amdgcn_sqrtf(fmaxf(q1, 1e-12f));
        float d2 = __builtin_amdgcn_sqrtf(fmaxf(q2, 1e-12f));
        float d3 = __builtin_amdgcn_sqrtf(fmaxf(q3, 1e-12f));
        float mean = (d1 + d2 + d3) * (1.f / 3.f);
        localc[p] = -2.f * ftanh(__builtin_amdgcn_rcpf(mean + 1e-6f));
    }

    {   // layer2: col-tile rT, row-tiles {2hT, 2hT+1}
        f32x4 h2[2];
        h2[0] = (f32x4){0.f,0.f,0.f,0.f};
        h2[1] = (f32x4){0.f,0.f,0.f,0.f};
        const int rt0 = 2 * hT;
#pragma unroll
        for (int ks = 0; ks < 4; ++ks) {
            int kb = ks * 64 + lk * 16;
            short8v aA = *(const short8v*)((const char*)h1B + swzh(16 * rt0 + lr, kb));
            short8v aB = *(const short8v*)((const char*)h1B + swzh(16 * rt0 + 16 + lr, kb));
            h2[0] = __builtin_amdgcn_mfma_f32_16x16x32_bf16(aA, w2f[ks], h2[0], 0, 0, 0);
            h2[1] = __builtin_amdgcn_mfma_f32_16x16x32_bf16(aB, w2f[ks], h2[1], 0, 0, 0);
        }
        float s4[2][4];
#pragma unroll
        for (int u = 0; u < 2; ++u)
#pragma unroll
            for (int e = 0; e < 4; ++e)
                s4[u][e] = fmaxf(h2[u][e] + cb2v, 0.f) * cw3v;
#pragma unroll
        for (int m = 1; m <= 8; m <<= 1) {
#pragma unroll
            for (int u = 0; u < 2; ++u)
#pragma unroll
                for (int e = 0; e < 4; ++e) s4[u][e] += __shfl_xor(s4[u][e], m);
        }
        if (lr == 0) {
#pragma unroll
            for (int u = 0; u < 2; ++u)
#pragma unroll
                for (int e = 0; e < 4; ++e)
                    ctxp[rT * 64 + (rt0 + u) * 16 + 4 * lk + e] = s4[u][e];
        }
    }

    {   // hier1: row-tile rT, col-half hT -> g1B
        f32x4 q = {0.f,0.f,0.f,0.f};
#pragma unroll
        for (int ks = 0; ks < 4; ++ks) {
            int kb = ks * 64 + lk * 16;
            short8v a = *(const short8v*)((const char*)posB + swzb(16 * rT + lr, kb));
            q = __builtin_amdgcn_mfma_f32_16x16x32_bf16(a, hw1f[ks], q, 0, 0, 0);
        }
        int j = 16 * hT + lr;
#pragma unroll
        for (int e = 0; e < 4; ++e) {
            int p = 16 * rT + 4 * lk + e;
            float v = fmaxf(q[e] + tdep[p] * u1v + hb1v, 0.f);
            *(short*)((char*)g1B + p * 64 + ((2 * j) ^ ((p & 3) << 4))) = (short)f2bf(v);
        }
    }
    __syncthreads();                                   // B4: g1B/ctxp/localc visible

    // ------- P4: hier2 + combine (even waves only; row-tile = w>>1) --------
    if (hT == 0) {
        short8v hw2f = ((const short8v*)hw2T)[lr * 4 + lk];
        float hb2v = hb2[lr], hw3v = hw3[lr];
        float hb3v = hb3[0], cb3v = cb3[0];
        int p2 = 16 * rT + lr;
        short8v a = *(const short8v*)((const char*)g1B + p2 * 64 + ((lk * 16) ^ ((p2 & 3) << 4)));
        f32x4 g2 = {0.f,0.f,0.f,0.f};
        g2 = __builtin_amdgcn_mfma_f32_16x16x32_bf16(a, hw2f, g2, 0, 0, 0);
        float sh[4];
#pragma unroll
        for (int e = 0; e < 4; ++e) sh[e] = ftanh(g2[e] + hb2v) * hw3v;
#pragma unroll
        for (int m = 1; m <= 8; m <<= 1) {
#pragma unroll
            for (int e = 0; e < 4; ++e) sh[e] += __shfl_xor(sh[e], m);
        }
        if (lr == 0) {
#pragma unroll
            for (int e = 0; e < 4; ++e) {
                int p = 16 * rT + 4 * lk + e;
                float ctxv = ctxp[p] + ctxp[64 + p] + ctxp[128 + p] + ctxp[192 + p] + cb3v;
                float comb = 0.5f * localc[p] + 0.3f * ctxv + 0.2f * (sh[e] + hb3v);
                out[(size_t)bt * 64 + p] = comb;
            }
        }
    }
}

// ---------------- K2a: per-16-bt partial sums over p ----------------
__global__ void reduce1(const float* __restrict__ comb, float* __restrict__ partials) {
    __shared__ float sm[256];
    int b = blockIdx.x, tid = threadIdx.x;
    const float* src = comb + (size_t)b * 1024;
    float s = 0.f;
#pragma unroll
    for (int k = 0; k < 4; ++k) s += src[tid + 256 * k];
    sm[tid] = s;
    __syncthreads();
    if (tid < 64) partials[b * 64 + tid] = sm[tid] + sm[tid + 64] + sm[tid + 128] + sm[tid + 192];
}

// ---------------- K2b: final mean + memory update ----------------
__global__ void reduce2(const float* __restrict__ partials, const float* __restrict__ mem,
                        float* __restrict__ newmem) {
    int p = threadIdx.x;  // 64 threads
    float s0 = 0.f, s1 = 0.f, s2 = 0.f, s3 = 0.f;
    for (int b = 0; b < 256; b += 4) {
        s0 += partials[(b + 0) * 64 + p];
        s1 += partials[(b + 1) * 64 + p];
        s2 += partials[(b + 2) * 64 + p];
        s3 += partials[(b + 3) * 64 + p];
    }
    float s = (s0 + s1) + (s2 + s3);
    newmem[p] = 0.9f * mem[p] + 0.1f * (s * (1.f / 4096.f));
}

// ---------------- K3: in-place smoothing + clip (float4) ----------------
__global__ void finalize(float* __restrict__ out, const float* __restrict__ newmem) {
    int t = blockIdx.x * 256 + threadIdx.x;      // 65536 threads x 4 elements
    float4v v = *(float4v*)(out + 4 * (size_t)t);
    float4v nm = *(const float4v*)(newmem + ((4 * t) & 63));
#pragma unroll
    for (int e = 0; e < 4; ++e) {
        float x = 0.9f * v[e] + 0.1f * nm[e];
        v[e] = fminf(fmaxf(x, -5.f), 2.f);
    }
    *(float4v*)(out + 4 * (size_t)t) = v;
}

extern "C" void kernel_launch(void* const* d_in, const int* in_sizes, int n_in,
                              void* d_out, int out_size, void* d_ws, size_t ws_size,
                              hipStream_t stream) {
    (void)in_sizes; (void)n_in; (void)out_size; (void)ws_size;
    const float* pos = (const float*)d_in[0];
    const float* ctx = (const float*)d_in[1];
    const float* dep = (const float*)d_in[2];
    const float* cw1 = (const float*)d_in[3];
    const float* cb1 = (const float*)d_in[4];
    const float* cw2 = (const float*)d_in[5];
    const float* cb2 = (const float*)d_in[6];
    const float* cw3 = (const float*)d_in[7];
    const float* cb3 = (const float*)d_in[8];
    const float* hw1 = (const float*)d_in[9];
    const float* hb1 = (const float*)d_in[10];
    const float* hw2 = (const float*)d_in[11];
    const float* hb2 = (const float*)d_in[12];
    const float* hw3 = (const float*)d_in[13];
    const float* hb3 = (const float*)d_in[14];
    const float* cmem = (const float*)d_in[15];
    float* out = (float*)d_out;
    float* ws = (float*)d_ws;
    float* partials = ws;                         // 16384 f
    float* newmem = ws + 16384;                   // 64 f
    unsigned short* wT = (unsigned short*)(ws + 16448);
    unsigned short* w1bT = wT;                    // 16384 us
    unsigned short* w2bT = wT + 16384;            // 8192 us
    unsigned short* hw1T = wT + 24576;            // 4096 us
    unsigned short* hw2T = wT + 28672;            // 512 us
    float* ctxW1 = ws + 31040;                    // 4096*128 f (2 MB)

    prep_weights<<<114, 256, 0, stream>>>(cw1, cw2, hw1, hw2, w1bT, w2bT, hw1T, hw2T);
    ctx_gemm<<<256, 256, 0, stream>>>(ctx, cw1, cb1, ctxW1);
    fused_main<<<4096, 512, 0, stream>>>(pos, dep, cb2, cw3, cb3,
                                         hw1, hb1, hb2, hw3, hb3,
                                         w1bT, w2bT, hw1T, hw2T, ctxW1, out);
    reduce1<<<256, 256, 0, stream>>>(out, partials);
    reduce2<<<1, 64, 0, stream>>>(partials, cmem, newmem);
    finalize<<<256, 256, 0, stream>>>(out, newmem);
}

// Round 12
// 83.703 us; speedup vs baseline: 1.2251x; 1.2251x over previous
//
#include <hip/hip_runtime.h>
#include <hip/hip_bf16.h>

typedef __attribute__((ext_vector_type(4))) float  float4v;
typedef __attribute__((ext_vector_type(2))) unsigned int uint2v;
typedef __attribute__((ext_vector_type(8))) short  short8v;
typedef __attribute__((ext_vector_type(4))) float  f32x4;

__device__ __forceinline__ unsigned short f2bf(float f) {
    unsigned int u = __float_as_uint(f);
    u += 0x7FFFu + ((u >> 16) & 1u);   // RNE
    return (unsigned short)(u >> 16);
}

// fast tanh: (t-1)/(t+1), t = 2^(2*log2e*x); clamp avoids inf*0 NaN.
__device__ __forceinline__ float ftanh(float x) {
    float s = fminf(x * 2.8853900817779268f, 115.0f);
    float t = exp2f(s);
    return (t - 1.0f) * __builtin_amdgcn_rcpf(t + 1.0f);
}

__device__ __forceinline__ int swzb(int row, int kbyte) {
    // row-major [R][128] bf16 rows (256B); XOR-swizzle bits 4-6 (G4).
    return row * 256 + (kbyte ^ ((row & 7) << 4));
}
__device__ __forceinline__ int swzh(int row, int kbyte) {
    // h1B swizzle: extra (row&8)<<2 spreads lk/lk+2 lanes across banks.
    return row * 256 + (kbyte ^ ((row & 7) << 4) ^ ((row & 8) << 2));
}

// ---------------- K0a: transpose + bf16-cast weights into ws ----------------
__global__ void prep_weights(const float* __restrict__ cw1, const float* __restrict__ cw2,
                             const float* __restrict__ hw1, const float* __restrict__ hw2,
                             unsigned short* __restrict__ w1bT, unsigned short* __restrict__ w2bT,
                             unsigned short* __restrict__ hw1T, unsigned short* __restrict__ hw2T) {
    int i = blockIdx.x * 256 + threadIdx.x;
    if (i < 16384) {                       // w1 top half T: [j<128][k<128]
        int j = i >> 7, k = i & 127;
        w1bT[i] = f2bf(cw1[k * 128 + j]);
    } else if (i < 24576) {                // w2 T: [j<64][k<128]
        int t = i - 16384; int j = t >> 7, k = t & 127;
        w2bT[t] = f2bf(cw2[k * 64 + j]);
    } else if (i < 28672) {                // hw1 top 128 rows T: [j<32][k<128]
        int t = i - 24576; int j = t >> 7, k = t & 127;
        hw1T[t] = f2bf(hw1[k * 32 + j]);
    } else if (i < 29184) {                // hw2 T: [j<16][k<32]
        int t = i - 28672; int j = t >> 5, k = t & 31;
        hw2T[t] = f2bf(hw2[k * 16 + j]);
    }
}

// ---------------- K0b: ctxW1[bt][j] = ctx[bt] @ W1_bot + cb1 (f32 exact) -----
__global__ __launch_bounds__(256) void ctx_gemm(const float* __restrict__ ctx,
                                                const float* __restrict__ cw1,
                                                const float* __restrict__ cb1,
                                                float* __restrict__ ctxW1) {
    __shared__ float ldsW[128 * 128];   // W1 bottom half [d][j]
    __shared__ float ldsC[16 * 128];    // 16 ctx rows
    const int tid = threadIdx.x;
    const int bt0 = blockIdx.x * 16;
    for (int i = tid; i < 16384; i += 256) {
        int d = i >> 7, j = i & 127;
        ldsW[i] = cw1[(128 + d) * 128 + j];
    }
    for (int i = tid; i < 2048; i += 256) ldsC[i] = ctx[bt0 * 128 + i];
    __syncthreads();
    const int j = tid & 127, half = tid >> 7;
    float acc[8];
    float bj = cb1[j];
#pragma unroll
    for (int k = 0; k < 8; ++k) acc[k] = bj;
    for (int d = 0; d < 128; ++d) {
        float wv = ldsW[d * 128 + j];
#pragma unroll
        for (int k = 0; k < 8; ++k) acc[k] += ldsC[(half * 8 + k) * 128 + d] * wv;
    }
#pragma unroll
    for (int k = 0; k < 8; ++k) ctxW1[(size_t)(bt0 + half * 8 + k) * 128 + j] = acc[k];
}

// ---------------- K1: fused per-(b,t) kernel — 4 barriers, reg-resident W ----
__global__ __launch_bounds__(256, 4) void fused_main(
    const float* __restrict__ pos_g, const float* __restrict__ dep_g,
    const float* __restrict__ cb2,  const float* __restrict__ cw3,
    const float* __restrict__ cb3,  const float* __restrict__ hw1,
    const float* __restrict__ hb1,  const float* __restrict__ hb2,
    const float* __restrict__ hw3,  const float* __restrict__ hb3,
    const unsigned short* __restrict__ w1bT, const unsigned short* __restrict__ w2bT,
    const unsigned short* __restrict__ hw1T, const unsigned short* __restrict__ hw2T,
    const float* __restrict__ ctxW1g, float* __restrict__ out)
{
    __shared__ __align__(16) short posB[64 * 128];   // 16 KB bf16 positions, swizzled
    __shared__ __align__(16) short h1B[64 * 128];    // 16 KB layer1 out (col-split write)
    __shared__ __align__(16) short g1B[64 * 32];     // 4 KB hier g1 (wave-private rows)
    __shared__ float tdep[64], diag[64], localc[64], hierc[64];
    __shared__ float ctxp[256];                      // [wave][row] layer2 col-partials

    const int bt  = blockIdx.x;
    const int tid = threadIdx.x;
    const int lane = tid & 63;
    const int w   = tid >> 6;
    const int lr  = lane & 15;   // frag row-in-16 / output col
    const int lk  = lane >> 4;   // k-subgroup (8 bf16 each)
    const int R   = w * 16;      // this wave's row base (Gram/kNN/hier)

    // ------- P0a: issue long-lived weight preloads (drain at B1 with staging) ----
    const short8v* w1p8 = (const short8v*)w1bT;
    const short8v* w2p8 = (const short8v*)w2bT;
    short8v w1f[2][4], w2f[4];
#pragma unroll
    for (int jtl = 0; jtl < 2; ++jtl)
#pragma unroll
        for (int ks = 0; ks < 4; ++ks)
            w1f[jtl][ks] = w1p8[(32 * w + jtl * 16 + lr) * 16 + ks * 4 + lk];
#pragma unroll
    for (int ks = 0; ks < 4; ++ks)
        w2f[ks] = w2p8[(16 * w + lr) * 16 + ks * 4 + lk];
    short8v hw2f = ((const short8v*)hw2T)[lr * 4 + lk];
    float cvals[2];
    cvals[0] = ctxW1g[(size_t)bt * 128 + 32 * w + lr];
    cvals[1] = ctxW1g[(size_t)bt * 128 + 32 * w + 16 + lr];
    float cb2v = cb2[16 * w + lr], cw3v = cw3[16 * w + lr], cb3v = cb3[0];
    float hb2v = hb2[lr], hw3v = hw3[lr], hb3v = hb3[0];

    // ------- P0b: stage positions (f32 -> bf16, swizzled) ----------------
    const float4v* pos4 = (const float4v*)(pos_g + (size_t)bt * 8192);
#pragma unroll
    for (int i = 0; i < 8; ++i) {
        int c = tid + 256 * i;           // 2048 float4 chunks
        int row = c >> 5, c4 = c & 31;
        float4v v = pos4[c];
        __hip_bfloat162 lo2 = __float22bfloat162_rn(make_float2(v[0], v[1]));
        __hip_bfloat162 hi2 = __float22bfloat162_rn(make_float2(v[2], v[3]));
        unsigned int u0, u1;
        __builtin_memcpy(&u0, &lo2, 4);
        __builtin_memcpy(&u1, &hi2, 4);
        uint2v uu = {u0, u1};
        *(uint2v*)((char*)posB + row * 256 + ((c4 * 8) ^ ((row & 7) << 4))) = uu;
    }
    if (tid < 64) tdep[tid] = ftanh(dep_g[bt * 64 + tid]);
    __syncthreads();                                   // B1: posB/tdep + preloads done

    // ---------------- P1: Gram = P @ P^T (64x64), diag = |p|^2 ----------------
    f32x4 g0 = {0.f,0.f,0.f,0.f}, g1t = {0.f,0.f,0.f,0.f},
          g2t = {0.f,0.f,0.f,0.f}, g3t = {0.f,0.f,0.f,0.f};
#pragma unroll
    for (int ks = 0; ks < 4; ++ks) {
        int kb = ks * 64 + lk * 16;
        short8v a = *(const short8v*)((const char*)posB + swzb(R + lr, kb));
        short8v b0 = *(const short8v*)((const char*)posB + swzb(0  + lr, kb));
        short8v b1 = *(const short8v*)((const char*)posB + swzb(16 + lr, kb));
        short8v b2 = *(const short8v*)((const char*)posB + swzb(32 + lr, kb));
        short8v b3 = *(const short8v*)((const char*)posB + swzb(48 + lr, kb));
        g0 = __builtin_amdgcn_mfma_f32_16x16x32_bf16(a, b0, g0, 0, 0, 0);
        g1t = __builtin_amdgcn_mfma_f32_16x16x32_bf16(a, b1, g1t, 0, 0, 0);
        g2t = __builtin_amdgcn_mfma_f32_16x16x32_bf16(a, b2, g2t, 0, 0, 0);
        g3t = __builtin_amdgcn_mfma_f32_16x16x32_bf16(a, b3, g3t, 0, 0, 0);
    }
    {   // diagonal: rows of this wave live in tile jt==w; static-select (rule #20)
        f32x4 gw = (w == 0) ? g0 : (w == 1) ? g1t : (w == 2) ? g2t : g3t;
        int e = lr & 3;
        float dv = (e == 0) ? gw[0] : (e == 1) ? gw[1] : (e == 2) ? gw[2] : gw[3];
        if (lk == (lr >> 2)) diag[R + lr] = dv;
    }
    __syncthreads();                                   // B2: diag visible

    // ---------------- P2: kNN (3-NN mean dist) -> localc LDS ----------------
    {
        float s0[4], s1[4], s2[4], s3[4];
#pragma unroll
        for (int e = 0; e < 4; ++e) {
            int p = R + 4 * lk + e;
            float dp = diag[p];
            s0[e] = s1[e] = s2[e] = s3[e] = 1e30f;
#pragma unroll
            for (int jt = 0; jt < 4; ++jt) {
                f32x4 gt = (jt == 0) ? g0 : (jt == 1) ? g1t : (jt == 2) ? g2t : g3t;
                float gv = (e == 0) ? gt[0] : (e == 1) ? gt[1] : (e == 2) ? gt[2] : gt[3];
                float d2 = dp + diag[jt * 16 + lr] - 2.f * gv;
                float c0 = fminf(s0[e], d2), m0 = fmaxf(s0[e], d2);
                float c1 = fminf(s1[e], m0), m1 = fmaxf(s1[e], m0);
                float c2 = fminf(s2[e], m1), m2 = fmaxf(s2[e], m1);
                float c3 = fminf(s3[e], m2);
                s0[e] = c0; s1[e] = c1; s2[e] = c2; s3[e] = c3;
            }
        }
#pragma unroll
        for (int m = 1; m <= 8; m <<= 1) {
#pragma unroll
            for (int e = 0; e < 4; ++e) {
                float t0 = __shfl_xor(s0[e], m);
                float t1 = __shfl_xor(s1[e], m);
                float t2 = __shfl_xor(s2[e], m);
                float t3 = __shfl_xor(s3[e], m);
                float r0 = fminf(s0[e], t3), r1 = fminf(s1[e], t2);
                float r2 = fminf(s2[e], t1), r3 = fminf(s3[e], t0);
                float a0 = fminf(r0, r2), b0 = fmaxf(r0, r2);
                float a1 = fminf(r1, r3), b1 = fmaxf(r1, r3);
                s0[e] = fminf(a0, a1); s1[e] = fmaxf(a0, a1);
                s2[e] = fminf(b0, b1); s3[e] = fmaxf(b0, b1);
            }
        }
        if (lr == 0) {
#pragma unroll
            for (int e = 0; e < 4; ++e) {
                float d1 = __builtin_amdgcn_sqrtf(fmaxf(s1[e], 1e-12f));
                float d2 = __builtin_amdgcn_sqrtf(fmaxf(s2[e], 1e-12f));
                float d3 = __builtin_amdgcn_sqrtf(fmaxf(s3[e], 1e-12f));
                float mean = (d1 + d2 + d3) * (1.f / 3.f);
                localc[R + 4 * lk + e] = -2.f * ftanh(__builtin_amdgcn_rcpf(mean + 1e-6f));
            }
        }
    }

    // -------- P3: layer1 col-split: wave w -> cols [32w,32w+32), all 64 rows ------
    {
        f32x4 h1a[4][2];
#pragma unroll
        for (int rt = 0; rt < 4; ++rt)
#pragma unroll
            for (int jtl = 0; jtl < 2; ++jtl) h1a[rt][jtl] = (f32x4){0.f,0.f,0.f,0.f};
#pragma unroll
        for (int ks = 0; ks < 4; ++ks) {
            int kb = ks * 64 + lk * 16;
#pragma unroll
            for (int rt = 0; rt < 4; ++rt) {
                short8v a = *(const short8v*)((const char*)posB + swzb(rt * 16 + lr, kb));
                h1a[rt][0] = __builtin_amdgcn_mfma_f32_16x16x32_bf16(a, w1f[0][ks], h1a[rt][0], 0, 0, 0);
                h1a[rt][1] = __builtin_amdgcn_mfma_f32_16x16x32_bf16(a, w1f[1][ks], h1a[rt][1], 0, 0, 0);
            }
        }
#pragma unroll
        for (int rt = 0; rt < 4; ++rt)
#pragma unroll
            for (int jtl = 0; jtl < 2; ++jtl) {
                int j = 32 * w + jtl * 16 + lr;
                float add = cvals[jtl];
#pragma unroll
                for (int e = 0; e < 4; ++e) {
                    int p = rt * 16 + 4 * lk + e;
                    float v = fmaxf(h1a[rt][jtl][e] + add, 0.f);
                    *(short*)((char*)h1B + swzh(p, 2 * j)) = (short)f2bf(v);
                }
            }
    }
    __syncthreads();                                   // B3: h1B complete (cross-wave)

    // -------- P4: layer2 col-split (cols [16w,16w+16), all rows) + col-reduce -----
    // issue hier weights now; they hide under P4's ds_reads/MFMAs
    const short8v* hw1p8 = (const short8v*)hw1T;
    short8v hw1f[2][4];
#pragma unroll
    for (int jt = 0; jt < 2; ++jt)
#pragma unroll
        for (int ks = 0; ks < 4; ++ks)
            hw1f[jt][ks] = hw1p8[(jt * 16 + lr) * 16 + ks * 4 + lk];
    float u1v[2], hb1v[2];
#pragma unroll
    for (int jt = 0; jt < 2; ++jt) { u1v[jt] = hw1[4096 + jt * 16 + lr]; hb1v[jt] = hb1[jt * 16 + lr]; }
    {
        f32x4 h2[4];
#pragma unroll
        for (int rt = 0; rt < 4; ++rt) h2[rt] = (f32x4){0.f,0.f,0.f,0.f};
#pragma unroll
        for (int ks = 0; ks < 4; ++ks) {
            int kb = ks * 64 + lk * 16;
#pragma unroll
            for (int rt = 0; rt < 4; ++rt) {
                short8v a = *(const short8v*)((const char*)h1B + swzh(rt * 16 + lr, kb));
                h2[rt] = __builtin_amdgcn_mfma_f32_16x16x32_bf16(a, w2f[ks], h2[rt], 0, 0, 0);
            }
        }
        float s4[4][4];
#pragma unroll
        for (int rt = 0; rt < 4; ++rt)
#pragma unroll
            for (int e = 0; e < 4; ++e)
                s4[rt][e] = fmaxf(h2[rt][e] + cb2v, 0.f) * cw3v;
#pragma unroll
        for (int m = 1; m <= 8; m <<= 1) {
#pragma unroll
            for (int rt = 0; rt < 4; ++rt)
#pragma unroll
                for (int e = 0; e < 4; ++e) s4[rt][e] += __shfl_xor(s4[rt][e], m);
        }
        if (lr == 0) {
#pragma unroll
            for (int rt = 0; rt < 4; ++rt)
#pragma unroll
                for (int e = 0; e < 4; ++e)
                    ctxp[w * 64 + rt * 16 + 4 * lk + e] = s4[rt][e];
        }
    }

    // -------- P5: hierarchy layer1 (row-split, own rows) + G1 writeout ------------
    {
        f32x4 q0 = {0.f,0.f,0.f,0.f}, q1 = {0.f,0.f,0.f,0.f};
#pragma unroll
        for (int ks = 0; ks < 4; ++ks) {
            int kb = ks * 64 + lk * 16;
            short8v a = *(const short8v*)((const char*)posB + swzb(R + lr, kb));
            q0 = __builtin_amdgcn_mfma_f32_16x16x32_bf16(a, hw1f[0][ks], q0, 0, 0, 0);
            q1 = __builtin_amdgcn_mfma_f32_16x16x32_bf16(a, hw1f[1][ks], q1, 0, 0, 0);
        }
#pragma unroll
        for (int jt = 0; jt < 2; ++jt) {
            int j = jt * 16 + lr;
#pragma unroll
            for (int e = 0; e < 4; ++e) {
                int p = R + 4 * lk + e;
                f32x4 qq = (jt == 0) ? q0 : q1;
                float v = fmaxf(qq[e] + tdep[p] * u1v[jt] + hb1v[jt], 0.f);
                *(short*)((char*)g1B + p * 64 + ((2 * j) ^ ((p & 3) << 4))) = (short)f2bf(v);
            }
        }
    }
    asm volatile("s_waitcnt lgkmcnt(0)" ::: "memory");   // g1B rows wave-private

    // -------- P6: hier layer2 (K=32) + tanh + layer3 reduce -> hierc LDS ----------
    {
        int p2 = R + lr;
        short8v a = *(const short8v*)((const char*)g1B + p2 * 64 + ((lk * 16) ^ ((p2 & 3) << 4)));
        f32x4 g2 = {0.f,0.f,0.f,0.f};
        g2 = __builtin_amdgcn_mfma_f32_16x16x32_bf16(a, hw2f, g2, 0, 0, 0);
        float sh[4];
#pragma unroll
        for (int e = 0; e < 4; ++e) sh[e] = ftanh(g2[e] + hb2v) * hw3v;
#pragma unroll
        for (int m = 1; m <= 8; m <<= 1) {
#pragma unroll
            for (int e = 0; e < 4; ++e) sh[e] += __shfl_xor(sh[e], m);
        }
        if (lr == 0) {
#pragma unroll
            for (int e = 0; e < 4; ++e) hierc[R + 4 * lk + e] = sh[e] + hb3v;
        }
    }
    __syncthreads();                                   // B4: localc/ctxp/hierc visible

    // ---------------- P7: combine + store ----------------
    if (tid < 64) {
        float ctxv = ctxp[tid] + ctxp[64 + tid] + ctxp[128 + tid] + ctxp[192 + tid] + cb3v;
        float comb = 0.5f * localc[tid] + 0.3f * ctxv + 0.2f * hierc[tid];
        out[(size_t)bt * 64 + tid] = comb;
    }
}

// ---------------- K2a: per-16-bt partial sums over p ----------------
__global__ void reduce1(const float* __restrict__ comb, float* __restrict__ partials) {
    __shared__ float sm[256];
    int b = blockIdx.x, tid = threadIdx.x;
    const float* src = comb + (size_t)b * 1024;
    float s = 0.f;
#pragma unroll
    for (int k = 0; k < 4; ++k) s += src[tid + 256 * k];
    sm[tid] = s;
    __syncthreads();
    if (tid < 64) partials[b * 64 + tid] = sm[tid] + sm[tid + 64] + sm[tid + 128] + sm[tid + 192];
}

// ---------------- K2b: final mean + memory update ----------------
__global__ void reduce2(const float* __restrict__ partials, const float* __restrict__ mem,
                        float* __restrict__ newmem) {
    int p = threadIdx.x;  // 64 threads
    float s0 = 0.f, s1 = 0.f, s2 = 0.f, s3 = 0.f;
    for (int b = 0; b < 256; b += 4) {
        s0 += partials[(b + 0) * 64 + p];
        s1 += partials[(b + 1) * 64 + p];
        s2 += partials[(b + 2) * 64 + p];
        s3 += partials[(b + 3) * 64 + p];
    }
    float s = (s0 + s1) + (s2 + s3);
    newmem[p] = 0.9f * mem[p] + 0.1f * (s * (1.f / 4096.f));
}

// ---------------- K3: in-place smoothing + clip (float4) ----------------
__global__ void finalize(float* __restrict__ out, const float* __restrict__ newmem) {
    int t = blockIdx.x * 256 + threadIdx.x;      // 65536 threads x 4 elements
    float4v v = *(float4v*)(out + 4 * (size_t)t);
    float4v nm = *(const float4v*)(newmem + ((4 * t) & 63));
#pragma unroll
    for (int e = 0; e < 4; ++e) {
        float x = 0.9f * v[e] + 0.1f * nm[e];
        v[e] = fminf(fmaxf(x, -5.f), 2.f);
    }
    *(float4v*)(out + 4 * (size_t)t) = v;
}

extern "C" void kernel_launch(void* const* d_in, const int* in_sizes, int n_in,
                              void* d_out, int out_size, void* d_ws, size_t ws_size,
                              hipStream_t stream) {
    (void)in_sizes; (void)n_in; (void)out_size; (void)ws_size;
    const float* pos = (const float*)d_in[0];
    const float* ctx = (const float*)d_in[1];
    const float* dep = (const float*)d_in[2];
    const float* cw1 = (const float*)d_in[3];
    const float* cb1 = (const float*)d_in[4];
    const float* cw2 = (const float*)d_in[5];
    const float* cb2 = (const float*)d_in[6];
    const float* cw3 = (const float*)d_in[7];
    const float* cb3 = (const float*)d_in[8];
    const float* hw1 = (const float*)d_in[9];
    const float* hb1 = (const float*)d_in[10];
    const float* hw2 = (const float*)d_in[11];
    const float* hb2 = (const float*)d_in[12];
    const float* hw3 = (const float*)d_in[13];
    const float* hb3 = (const float*)d_in[14];
    const float* cmem = (const float*)d_in[15];
    float* out = (float*)d_out;
    float* ws = (float*)d_ws;
    float* partials = ws;                         // 16384 f
    float* newmem = ws + 16384;                   // 64 f
    unsigned short* wT = (unsigned short*)(ws + 16448);
    unsigned short* w1bT = wT;                    // 16384 us
    unsigned short* w2bT = wT + 16384;            // 8192 us
    unsigned short* hw1T = wT + 24576;            // 4096 us
    unsigned short* hw2T = wT + 28672;            // 512 us
    float* ctxW1 = ws + 31040;                    // 4096*128 f (2 MB)

    prep_weights<<<114, 256, 0, stream>>>(cw1, cw2, hw1, hw2, w1bT, w2bT, hw1T, hw2T);
    ctx_gemm<<<256, 256, 0, stream>>>(ctx, cw1, cb1, ctxW1);
    fused_main<<<4096, 256, 0, stream>>>(pos, dep, cb2, cw3, cb3,
                                         hw1, hb1, hb2, hw3, hb3,
                                         w1bT, w2bT, hw1T, hw2T, ctxW1, out);
    reduce1<<<256, 256, 0, stream>>>(out, partials);
    reduce2<<<1, 64, 0, stream>>>(partials, cmem, newmem);
    finalize<<<256, 256, 0, stream>>>(out, newmem);
}